// Round 12
// baseline (116.216 us; speedup 1.0000x reference)
//
#include <hip/hip_runtime.h>

// ---------------------------------------------------------------------------
// Fused 5-layer GRU (SEQ=1, h0=0) + FC for MI355X (gfx950).  Round 13.
//
// R13: 3-tile interleave.  Pipe accounting at R12 (wall 126us): VALU issue
// ~78us + LDS pipe ~45us (70 ds_read_b128/pair x 12cy x 128 pairs/CU), and
// they barely overlap.  The 70 reads/iteration (30 A-frag + 30 bias + 10 cn)
// are tile-count-invariant, so T=2 -> T=3 cuts per-tile LDS traffic by 33%
// (LDS busy 45 -> 30us/CU) and adds a third independent dependency chain.
// Register budget: 18 live accs (72) + 3 B-frags (12) + FC/OB (16) + temps
// fits under the 128 cap (T=2 measured 52; T=4's 96-VGPR acc set would not).
// Tail (65536 = 3*21845+1): wave-uniform validity guards, clamped loads,
// guarded stores.
//
// Kept from R12: XOR-swizzled stride-32 LDS weights (33280 B total).
// Kept from R11: FC weights + fc_b in registers; grid 1024.
// Kept from R10: single-plane fp16 MFMA, cvt_pkrtz pack, permlane C->B.
// Kept from R9: hardware v_rcp, exp2 scales folded into staged weights.
//
// Orientation: C^T = W @ h^T  (A = weight tile [gate][k], B = h^T [k][batch]).
// MFMA C/D layout (16x16x32): col = lane&15 = BATCH, row = q*4+i = gate row.
// ---------------------------------------------------------------------------

typedef __attribute__((ext_vector_type(8))) _Float16 f16x8;
typedef __attribute__((ext_vector_type(4))) float f32x4;
typedef __attribute__((ext_vector_type(2))) float f32x2;
typedef __attribute__((ext_vector_type(4))) unsigned int u32x4;

#define NLAYER 5
#define NT     512 // block threads (8 waves)

__device__ __forceinline__ float fexp2(float x) {
#if __has_builtin(__builtin_amdgcn_exp2f)
    return __builtin_amdgcn_exp2f(x);
#else
    return exp2f(x);
#endif
}
__device__ __forceinline__ float frcp(float x) {
#if __has_builtin(__builtin_amdgcn_rcpf)
    return __builtin_amdgcn_rcpf(x);
#else
    return 1.0f / x;
#endif
}

// pack two f32 -> two fp16 (RTZ) in one word; rel err <= 2^-10, far below
// the fp16 weight quant (2^-11 RNE) + ref tolerance.
__device__ __forceinline__ unsigned cvt2(float f0, float f1) {
    unsigned r;
    asm("v_cvt_pkrtz_f16_f32 %0, %1, %2" : "=v"(r) : "v"(f0), "v"(f1));
    return r;
}

__device__ __forceinline__ f32x4 mfma16h(f16x8 a, f16x8 b, f32x4 c) {
    return __builtin_amdgcn_mfma_f32_16x16x32_f16(a, b, c, 0, 0, 0);
}

// In-register 16-lane-group exchange (gfx950):
//   in : x = [X0,X1,X2,X3], y = [Y0,Y1,Y2,Y3]   (16-lane groups)
//   out: x = [X0,X2,Y0,Y2], y = [X1,X3,Y1,Y3]
__device__ __forceinline__ void xpose_pair(unsigned &x, unsigned &y) {
    asm("v_permlane32_swap_b32 %0, %1" : "+v"(x), "+v"(y));
    asm("v_permlane16_swap_b32 %0, %1" : "+v"(x), "+v"(y));
}

__device__ __forceinline__ f32x2 mk2(float a, float b) { f32x2 v; v.x = a; v.y = b; return v; }
__device__ __forceinline__ f32x2 exp2v(f32x2 v) { f32x2 r; r.x = fexp2(v.x); r.y = fexp2(v.y); return r; }
__device__ __forceinline__ f32x2 rcpv(f32x2 v)  { f32x2 r; r.x = frcp(v.x);  r.y = frcp(v.y);  return r; }

// h = (1-z)*n = sigmoid(-az)*tanh(an + sigmoid(ar)*cn)
//   = [ez*(1-en)] / [(1+ez)*(1+en)]
// Args are PRE-SCALED at staging: ar,az by -log2e; an,cn by -2log2e, so
// er = exp2(ar'), ez = exp2(az'), en = exp2(an' + r*cn') directly.
__device__ __forceinline__ f32x2 gru_act2(f32x2 ar, f32x2 az, f32x2 an, f32x2 cn) {
    f32x2 er  = exp2v(ar);
    f32x2 ez  = exp2v(az);
    f32x2 r   = rcpv(er + 1.0f);
    f32x2 a2  = an + r * cn;
    f32x2 en  = exp2v(a2);
    f32x2 num = ez - ez * en;
    f32x2 den = (ez + 1.0f) * (en + 1.0f);
    return num * rcpv(den);
}

struct __align__(16) Lds {
    _Float16 wA[NLAYER * 96 * 32];                // 30720 B  [l][gate-row][k], XOR-swizzled
    float bsum[NLAYER * 96];                      //  1920 B  scaled biases
    float cn_[NLAYER * 32];                      //   640 B  scaled b_hh n-gate
};                                                // total 33280 B

union BU { u32x4 w; f16x8 v; };

__global__ __launch_bounds__(NT, 4) void gru_fused(
    const float* __restrict__ x, const float* __restrict__ w_ih,
    const float* __restrict__ b_ih, const float* __restrict__ b_hh,
    const float* __restrict__ fc_w, const float* __restrict__ fc_b,
    float* __restrict__ out, int nTiles)
{
    __shared__ Lds s;
    const int tid = threadIdx.x;
    const float NL2E = -1.4426950408889634f;  // -log2(e)

    // ---- stage GRU weights / biases into LDS (once per block), pre-scaled.
    // Swizzle: element i stored at i ^ ((row&7)<<3). ----
    for (int i = tid; i < NLAYER * 96 * 32; i += NT) {
        int r = i >> 5;
        int g = r % 96;                         // gate row within layer
        float sc = (g < 64) ? NL2E : 2.0f * NL2E;
        s.wA[i ^ ((r & 7) << 3)] = (_Float16)(w_ih[i] * sc);   // RNE, rel 2^-11
    }
    for (int i = tid; i < NLAYER * 96; i += NT) {
        int c = i % 96;
        float v = b_ih[i] + (c < 64 ? b_hh[i] : 0.0f);
        s.bsum[i] = v * ((c < 64) ? NL2E : 2.0f * NL2E);
    }
    for (int i = tid; i < NLAYER * 32; i += NT) {
        int l = i >> 5, c = i & 31;
        s.cn_[i] = b_hh[l * 96 + 64 + c] * (2.0f * NL2E);
    }
    __syncthreads();

    const int lane = tid & 63;
    const int n0 = lane & 15;     // batch-col (B n-index / C col); A row m
    const int q  = lane >> 4;     // k-group (A/B), row-group (C/D)
    const int aBase = ((n0 * 32) + q * 8) ^ ((n0 & 7) << 3);  // swizzled A-frag idx

    // ---- FC weights + bias in registers (loop-invariant, 16 VGPR) ----
    f16x8 F0, F1;
    {
        const float* p0 = fc_w + (size_t)(n0 * 32 + q * 8);
        const float* p1 = fc_w + (size_t)((16 + n0) * 32 + q * 8);
        f32x4 a0 = *(const f32x4*)p0, a1 = *(const f32x4*)(p0 + 4);
        f32x4 b0 = *(const f32x4*)p1, b1 = *(const f32x4*)(p1 + 4);
        BU U0, U1;
        U0.w[0] = cvt2(a0[0], a0[1]); U0.w[1] = cvt2(a0[2], a0[3]);
        U0.w[2] = cvt2(a1[0], a1[1]); U0.w[3] = cvt2(a1[2], a1[3]);
        U1.w[0] = cvt2(b0[0], b0[1]); U1.w[1] = cvt2(b0[2], b0[3]);
        U1.w[2] = cvt2(b1[0], b1[1]); U1.w[3] = cvt2(b1[2], b1[3]);
        F0 = U0.v; F1 = U1.v;
    }
    f32x4 OB0 = *(const f32x4*)(fc_b + q * 4);
    f32x4 OB1 = *(const f32x4*)(fc_b + 16 + q * 4);

    const int waveId  = (int)((blockIdx.x * (unsigned)NT + tid) >> 6);
    const int nWavesG = (int)((gridDim.x * (unsigned)NT) >> 6);
    const int nGroups = (nTiles + 2) / 3;

    for (int g = waveId; g < nGroups; g += nWavesG) {
        const int t0 = g * 3;
        const int rowBase = t0 * 16;
        const bool v1 = (t0 + 1) < nTiles;     // wave-uniform
        const bool v2 = (t0 + 2) < nTiles;
        const int ro1 = v1 ? 16 : 0;           // clamp invalid tiles to tile 0
        const int ro2 = v2 ? 32 : 0;

        // ---- load x as fp16 B-frags for 3 tiles ----
        f16x8 b[3];
        {
            const float* xp0 = x + (size_t)(rowBase + n0) * 32 + q * 8;
            const float* xp1 = x + (size_t)(rowBase + ro1 + n0) * 32 + q * 8;
            const float* xp2 = x + (size_t)(rowBase + ro2 + n0) * 32 + q * 8;
            f32x4 xa0 = *(const f32x4*)xp0, xb0 = *(const f32x4*)(xp0 + 4);
            f32x4 xa1 = *(const f32x4*)xp1, xb1 = *(const f32x4*)(xp1 + 4);
            f32x4 xa2 = *(const f32x4*)xp2, xb2 = *(const f32x4*)(xp2 + 4);
            BU U;
            U.w[0] = cvt2(xa0[0], xa0[1]); U.w[1] = cvt2(xa0[2], xa0[3]);
            U.w[2] = cvt2(xb0[0], xb0[1]); U.w[3] = cvt2(xb0[2], xb0[3]);
            b[0] = U.v;
            U.w[0] = cvt2(xa1[0], xa1[1]); U.w[1] = cvt2(xa1[2], xa1[3]);
            U.w[2] = cvt2(xb1[0], xb1[1]); U.w[3] = cvt2(xb1[2], xb1[3]);
            b[1] = U.v;
            U.w[0] = cvt2(xa2[0], xa2[1]); U.w[1] = cvt2(xa2[2], xa2[3]);
            U.w[2] = cvt2(xb2[0], xb2[1]); U.w[3] = cvt2(xb2[2], xb2[3]);
            b[2] = U.v;
        }

        #pragma unroll
        for (int l = 0; l < NLAYER; ++l) {
            const _Float16* wb = s.wA + l * 96 * 32;
            const float* bs = s.bsum + l * 96;

            f32x4 cR0[3], cR1[3], cZ0[3], cZ1[3], cN0[3], cN1[3];

            // per gate-tile: 1 swizzled A-frag read + 1 bias read -> 3 MFMAs
            // (one per batch-tile), each initing from bias via D != C.
            {
                f16x8 a = *(const f16x8*)(wb + aBase + 0 * 512);
                f32x4 cb = *(const f32x4*)(bs + 0 + q * 4);
                #pragma unroll
                for (int j = 0; j < 3; ++j) cR0[j] = mfma16h(a, b[j], cb);
            }
            {
                f16x8 a = *(const f16x8*)(wb + aBase + 1 * 512);
                f32x4 cb = *(const f32x4*)(bs + 16 + q * 4);
                #pragma unroll
                for (int j = 0; j < 3; ++j) cR1[j] = mfma16h(a, b[j], cb);
            }
            {
                f16x8 a = *(const f16x8*)(wb + aBase + 2 * 512);
                f32x4 cb = *(const f32x4*)(bs + 32 + q * 4);
                #pragma unroll
                for (int j = 0; j < 3; ++j) cZ0[j] = mfma16h(a, b[j], cb);
            }
            {
                f16x8 a = *(const f16x8*)(wb + aBase + 3 * 512);
                f32x4 cb = *(const f32x4*)(bs + 48 + q * 4);
                #pragma unroll
                for (int j = 0; j < 3; ++j) cZ1[j] = mfma16h(a, b[j], cb);
            }
            {
                f16x8 a = *(const f16x8*)(wb + aBase + 4 * 512);
                f32x4 cb = *(const f32x4*)(bs + 64 + q * 4);
                #pragma unroll
                for (int j = 0; j < 3; ++j) cN0[j] = mfma16h(a, b[j], cb);
            }
            {
                f16x8 a = *(const f16x8*)(wb + aBase + 5 * 512);
                f32x4 cb = *(const f32x4*)(bs + 80 + q * 4);
                #pragma unroll
                for (int j = 0; j < 3; ++j) cN1[j] = mfma16h(a, b[j], cb);
            }

            f32x4 vc0 = *(const f32x4*)(s.cn_ + l * 32 + 0  + q * 4);
            f32x4 vc1 = *(const f32x4*)(s.cn_ + l * 32 + 16 + q * 4);

            // ---- activations + pack + permlane transform, per tile ----
            #pragma unroll
            for (int j = 0; j < 3; ++j) {
                f32x2 hA = gru_act2(mk2(cR0[j][0], cR0[j][1]), mk2(cZ0[j][0], cZ0[j][1]),
                                    mk2(cN0[j][0], cN0[j][1]), mk2(vc0[0], vc0[1]));
                f32x2 hB = gru_act2(mk2(cR0[j][2], cR0[j][3]), mk2(cZ0[j][2], cZ0[j][3]),
                                    mk2(cN0[j][2], cN0[j][3]), mk2(vc0[2], vc0[3]));
                f32x2 hC = gru_act2(mk2(cR1[j][0], cR1[j][1]), mk2(cZ1[j][0], cZ1[j][1]),
                                    mk2(cN1[j][0], cN1[j][1]), mk2(vc1[0], vc1[1]));
                f32x2 hD = gru_act2(mk2(cR1[j][2], cR1[j][3]), mk2(cZ1[j][2], cZ1[j][3]),
                                    mk2(cN1[j][2], cN1[j][3]), mk2(vc1[2], vc1[3]));
                unsigned hw0 = cvt2(hA.x, hA.y);   // hids 4q+{0,1}
                unsigned hw1 = cvt2(hB.x, hB.y);   // hids 4q+{2,3}
                unsigned hw2 = cvt2(hC.x, hC.y);   // hids 16+4q+{0,1}
                unsigned hw3 = cvt2(hD.x, hD.y);   // hids 16+4q+{2,3}
                xpose_pair(hw0, hw2);   // hw0 -> B elems {0,1}, hw2 -> {4,5}
                xpose_pair(hw1, hw3);   // hw1 -> B elems {2,3}, hw3 -> {6,7}
                BU T;
                T.w[0] = hw0; T.w[1] = hw1; T.w[2] = hw2; T.w[3] = hw3;
                b[j] = T.v;
            }
        }

        // ---- FC: out^T = fc_w @ h5^T + fc_b, all tiles (regs only) ----
        f32x4 o0[3], o1[3];
        #pragma unroll
        for (int j = 0; j < 3; ++j) {
            o0[j] = mfma16h(F0, b[j], OB0);
            o1[j] = mfma16h(F1, b[j], OB1);
        }

        // lane holds out[batch][emb = t*16 + q*4 + i]
        {
            float* op = out + (size_t)(rowBase + n0) * 32;
            *(f32x4*)(op + 0  + q * 4) = o0[0];
            *(f32x4*)(op + 16 + q * 4) = o1[0];
        }
        if (v1) {
            float* op = out + (size_t)(rowBase + 16 + n0) * 32;
            *(f32x4*)(op + 0  + q * 4) = o0[1];
            *(f32x4*)(op + 16 + q * 4) = o1[1];
        }
        if (v2) {
            float* op = out + (size_t)(rowBase + 32 + n0) * 32;
            *(f32x4*)(op + 0  + q * 4) = o0[2];
            *(f32x4*)(op + 16 + q * 4) = o1[2];
        }
    }
}

extern "C" void kernel_launch(void* const* d_in, const int* in_sizes, int n_in,
                              void* d_out, int out_size, void* d_ws, size_t ws_size,
                              hipStream_t stream) {
    (void)n_in; (void)d_ws; (void)ws_size; (void)out_size;
    const float* x    = (const float*)d_in[0];
    const float* w_ih = (const float*)d_in[1];
    // d_in[2] = w_hh: unused (h0 == 0, T == 1)
    const float* b_ih = (const float*)d_in[3];
    const float* b_hh = (const float*)d_in[4];
    const float* fc_w = (const float*)d_in[5];
    const float* fc_b = (const float*)d_in[6];
    float* out = (float*)d_out;

    const int batch  = in_sizes[0] / 32;   // 1048576
    const int nTiles = batch / 16;         // 65536 -> 21846 groups of 3

    // 1024 blocks x 512 thr, 8192 waves, ~2.67 groups/wave grid-stride.
    // LDS 33280 B; launch_bounds(512,4) keeps the allocator at the 128 cap
    // (estimated live ~110-120; FETCH_SIZE is the spill tripwire).
    gru_fused<<<1024, NT, 0, stream>>>(x, w_ih, b_ih, b_hh, fc_w, fc_b, out, nTiles);
}

// Round 13
// 110.998 us; speedup vs baseline: 1.0470x; 1.0470x over previous
//
#include <hip/hip_runtime.h>

// ---------------------------------------------------------------------------
// Fused 5-layer GRU (SEQ=1, h0=0) + FC for MI355X (gfx950).  Round 14.
//
// R14: revert T=3 (spilled: FETCH 66->86MB, WRITE 131->156MB scratch) back
// to the proven T=2 structure, and attack the REAL residency limiter:
// reported VGPR_Count (52-64) excludes MFMA accumulators; combined unified-
// file demand at T=2 is ~112 regs -> only 4 waves/SIMD under (512,4), which
// matches the stuck 34-38% occupancy AND the near-serial pipe sum
// (VALU 78us + LDS 30us + MFMA 14us ~ wall 124us).  Change launch_bounds
// to (512,5): cap ~96-102 combined, a ~10-16 reg squeeze the allocator can
// absorb via remat (R5's disaster was a 27-reg deficit; this is half, on a
// smaller kernel).  If it fits: 5 waves/SIMD = +25% TLP -> pipes overlap.
// Tripwire: FETCH_SIZE >100MB = spill -> revert next round.
//
// Kept from R12: XOR-swizzled stride-32 LDS weights (33280 B), grid 1024.
// Kept from R11: FC weights + fc_b in registers.
// Kept from R10: single-plane fp16 MFMA, cvt_pkrtz pack, permlane C->B.
// Kept from R9: hardware v_rcp, exp2 scales folded into staged weights.
// Kept from R7: 2-tile interleave, shared A-frag/bias reads, MFMA D!=C
// bias init.
//
// Orientation: C^T = W @ h^T  (A = weight tile [gate][k], B = h^T [k][batch]).
// MFMA C/D layout (16x16x32): col = lane&15 = BATCH, row = q*4+i = gate row.
// ---------------------------------------------------------------------------

typedef __attribute__((ext_vector_type(8))) _Float16 f16x8;
typedef __attribute__((ext_vector_type(4))) float f32x4;
typedef __attribute__((ext_vector_type(2))) float f32x2;
typedef __attribute__((ext_vector_type(4))) unsigned int u32x4;

#define NLAYER 5
#define NT     512 // block threads (8 waves)

__device__ __forceinline__ float fexp2(float x) {
#if __has_builtin(__builtin_amdgcn_exp2f)
    return __builtin_amdgcn_exp2f(x);
#else
    return exp2f(x);
#endif
}
__device__ __forceinline__ float frcp(float x) {
#if __has_builtin(__builtin_amdgcn_rcpf)
    return __builtin_amdgcn_rcpf(x);
#else
    return 1.0f / x;
#endif
}

// pack two f32 -> two fp16 (RTZ) in one word; rel err <= 2^-10, far below
// the fp16 weight quant (2^-11 RNE) + ref tolerance.
__device__ __forceinline__ unsigned cvt2(float f0, float f1) {
    unsigned r;
    asm("v_cvt_pkrtz_f16_f32 %0, %1, %2" : "=v"(r) : "v"(f0), "v"(f1));
    return r;
}

__device__ __forceinline__ f32x4 mfma16h(f16x8 a, f16x8 b, f32x4 c) {
    return __builtin_amdgcn_mfma_f32_16x16x32_f16(a, b, c, 0, 0, 0);
}

// In-register 16-lane-group exchange (gfx950):
//   in : x = [X0,X1,X2,X3], y = [Y0,Y1,Y2,Y3]   (16-lane groups)
//   out: x = [X0,X2,Y0,Y2], y = [X1,X3,Y1,Y3]
__device__ __forceinline__ void xpose_pair(unsigned &x, unsigned &y) {
    asm("v_permlane32_swap_b32 %0, %1" : "+v"(x), "+v"(y));
    asm("v_permlane16_swap_b32 %0, %1" : "+v"(x), "+v"(y));
}

__device__ __forceinline__ f32x2 mk2(float a, float b) { f32x2 v; v.x = a; v.y = b; return v; }
__device__ __forceinline__ f32x2 exp2v(f32x2 v) { f32x2 r; r.x = fexp2(v.x); r.y = fexp2(v.y); return r; }
__device__ __forceinline__ f32x2 rcpv(f32x2 v)  { f32x2 r; r.x = frcp(v.x);  r.y = frcp(v.y);  return r; }

// h = (1-z)*n = sigmoid(-az)*tanh(an + sigmoid(ar)*cn)
//   = [ez*(1-en)] / [(1+ez)*(1+en)]
// Args are PRE-SCALED at staging: ar,az by -log2e; an,cn by -2log2e, so
// er = exp2(ar'), ez = exp2(az'), en = exp2(an' + r*cn') directly.
__device__ __forceinline__ f32x2 gru_act2(f32x2 ar, f32x2 az, f32x2 an, f32x2 cn) {
    f32x2 er  = exp2v(ar);
    f32x2 ez  = exp2v(az);
    f32x2 r   = rcpv(er + 1.0f);
    f32x2 a2  = an + r * cn;
    f32x2 en  = exp2v(a2);
    f32x2 num = ez - ez * en;
    f32x2 den = (ez + 1.0f) * (en + 1.0f);
    return num * rcpv(den);
}

struct __align__(16) Lds {
    _Float16 wA[NLAYER * 96 * 32];                // 30720 B  [l][gate-row][k], XOR-swizzled
    float bsum[NLAYER * 96];                      //  1920 B  scaled biases
    float cn_[NLAYER * 32];                       //   640 B  scaled b_hh n-gate
};                                                // total 33280 B

union BU { u32x4 w; f16x8 v; };

__global__ __launch_bounds__(NT, 5) void gru_fused(
    const float* __restrict__ x, const float* __restrict__ w_ih,
    const float* __restrict__ b_ih, const float* __restrict__ b_hh,
    const float* __restrict__ fc_w, const float* __restrict__ fc_b,
    float* __restrict__ out, int nPairs)
{
    __shared__ Lds s;
    const int tid = threadIdx.x;
    const float NL2E = -1.4426950408889634f;  // -log2(e)

    // ---- stage GRU weights / biases into LDS (once per block), pre-scaled.
    // Swizzle: element i stored at i ^ ((row&7)<<3). ----
    for (int i = tid; i < NLAYER * 96 * 32; i += NT) {
        int r = i >> 5;
        int g = r % 96;                         // gate row within layer
        float sc = (g < 64) ? NL2E : 2.0f * NL2E;
        s.wA[i ^ ((r & 7) << 3)] = (_Float16)(w_ih[i] * sc);   // RNE, rel 2^-11
    }
    for (int i = tid; i < NLAYER * 96; i += NT) {
        int c = i % 96;
        float v = b_ih[i] + (c < 64 ? b_hh[i] : 0.0f);
        s.bsum[i] = v * ((c < 64) ? NL2E : 2.0f * NL2E);
    }
    for (int i = tid; i < NLAYER * 32; i += NT) {
        int l = i >> 5, c = i & 31;
        s.cn_[i] = b_hh[l * 96 + 64 + c] * (2.0f * NL2E);
    }
    __syncthreads();

    const int lane = tid & 63;
    const int n0 = lane & 15;     // batch-col (B n-index / C col); A row m
    const int q  = lane >> 4;     // k-group (A/B), row-group (C/D)
    const int aBase = ((n0 * 32) + q * 8) ^ ((n0 & 7) << 3);  // swizzled A-frag idx

    // ---- FC weights + bias in registers (loop-invariant, 16 VGPR) ----
    f16x8 F0, F1;
    {
        const float* p0 = fc_w + (size_t)(n0 * 32 + q * 8);
        const float* p1 = fc_w + (size_t)((16 + n0) * 32 + q * 8);
        f32x4 a0 = *(const f32x4*)p0, a1 = *(const f32x4*)(p0 + 4);
        f32x4 b0 = *(const f32x4*)p1, b1 = *(const f32x4*)(p1 + 4);
        BU U0, U1;
        U0.w[0] = cvt2(a0[0], a0[1]); U0.w[1] = cvt2(a0[2], a0[3]);
        U0.w[2] = cvt2(a1[0], a1[1]); U0.w[3] = cvt2(a1[2], a1[3]);
        U1.w[0] = cvt2(b0[0], b0[1]); U1.w[1] = cvt2(b0[2], b0[3]);
        U1.w[2] = cvt2(b1[0], b1[1]); U1.w[3] = cvt2(b1[2], b1[3]);
        F0 = U0.v; F1 = U1.v;
    }
    f32x4 OB0 = *(const f32x4*)(fc_b + q * 4);
    f32x4 OB1 = *(const f32x4*)(fc_b + 16 + q * 4);

    const int waveId  = (int)((blockIdx.x * (unsigned)NT + tid) >> 6);
    const int nWavesG = (int)((gridDim.x * (unsigned)NT) >> 6);

    for (int t = waveId; t < nPairs; t += nWavesG) {
        const int rowBase = t * 32;  // tile A rows +0..15, tile B rows +16..31

        // ---- load x as fp16 B-frags for both tiles ----
        const float* xpA = x + (size_t)(rowBase + n0) * 32 + q * 8;
        const float* xpB = x + (size_t)(rowBase + 16 + n0) * 32 + q * 8;
        f32x4 xaA = *(const f32x4*)xpA, xbA = *(const f32x4*)(xpA + 4);
        f32x4 xaB = *(const f32x4*)xpB, xbB = *(const f32x4*)(xpB + 4);
        BU BA, BB;
        BA.w[0] = cvt2(xaA[0], xaA[1]); BA.w[1] = cvt2(xaA[2], xaA[3]);
        BA.w[2] = cvt2(xbA[0], xbA[1]); BA.w[3] = cvt2(xbA[2], xbA[3]);
        BB.w[0] = cvt2(xaB[0], xaB[1]); BB.w[1] = cvt2(xaB[2], xaB[3]);
        BB.w[2] = cvt2(xbB[0], xbB[1]); BB.w[3] = cvt2(xbB[2], xbB[3]);
        f16x8 bA = BA.v, bB = BB.v;

        #pragma unroll
        for (int l = 0; l < NLAYER; ++l) {
            const _Float16* wb = s.wA + l * 96 * 32;
            const float* bs = s.bsum + l * 96;

            f32x4 cR0A, cR1A, cZ0A, cZ1A, cN0A, cN1A;
            f32x4 cR0B, cR1B, cZ0B, cZ1B, cN0B, cN1B;

            // per gate-tile: 1 swizzled A-frag LDS read + 1 bias read -> 2
            // MFMAs (one per batch-tile), each initing from bias via D != C.
            // gate g offset = g*512 elements (multiple of 64 -> swizzle-safe).
            {
                f16x8 a = *(const f16x8*)(wb + aBase + 0 * 512);
                f32x4 cb = *(const f32x4*)(bs + 0 + q * 4);
                cR0A = mfma16h(a, bA, cb);
                cR0B = mfma16h(a, bB, cb);
            }
            {
                f16x8 a = *(const f16x8*)(wb + aBase + 1 * 512);
                f32x4 cb = *(const f32x4*)(bs + 16 + q * 4);
                cR1A = mfma16h(a, bA, cb);
                cR1B = mfma16h(a, bB, cb);
            }
            {
                f16x8 a = *(const f16x8*)(wb + aBase + 2 * 512);
                f32x4 cb = *(const f32x4*)(bs + 32 + q * 4);
                cZ0A = mfma16h(a, bA, cb);
                cZ0B = mfma16h(a, bB, cb);
            }
            {
                f16x8 a = *(const f16x8*)(wb + aBase + 3 * 512);
                f32x4 cb = *(const f32x4*)(bs + 48 + q * 4);
                cZ1A = mfma16h(a, bA, cb);
                cZ1B = mfma16h(a, bB, cb);
            }
            {
                f16x8 a = *(const f16x8*)(wb + aBase + 4 * 512);
                f32x4 cb = *(const f32x4*)(bs + 64 + q * 4);
                cN0A = mfma16h(a, bA, cb);
                cN0B = mfma16h(a, bB, cb);
            }
            {
                f16x8 a = *(const f16x8*)(wb + aBase + 5 * 512);
                f32x4 cb = *(const f32x4*)(bs + 80 + q * 4);
                cN1A = mfma16h(a, bA, cb);
                cN1B = mfma16h(a, bB, cb);
            }

            f32x4 vc0 = *(const f32x4*)(s.cn_ + l * 32 + 0  + q * 4);
            f32x4 vc1 = *(const f32x4*)(s.cn_ + l * 32 + 16 + q * 4);

            // ---- activations + pack + permlane transform, tile A ----
            {
                f32x2 hA = gru_act2(mk2(cR0A[0], cR0A[1]), mk2(cZ0A[0], cZ0A[1]),
                                    mk2(cN0A[0], cN0A[1]), mk2(vc0[0], vc0[1]));
                f32x2 hB = gru_act2(mk2(cR0A[2], cR0A[3]), mk2(cZ0A[2], cZ0A[3]),
                                    mk2(cN0A[2], cN0A[3]), mk2(vc0[2], vc0[3]));
                f32x2 hC = gru_act2(mk2(cR1A[0], cR1A[1]), mk2(cZ1A[0], cZ1A[1]),
                                    mk2(cN1A[0], cN1A[1]), mk2(vc1[0], vc1[1]));
                f32x2 hD = gru_act2(mk2(cR1A[2], cR1A[3]), mk2(cZ1A[2], cZ1A[3]),
                                    mk2(cN1A[2], cN1A[3]), mk2(vc1[2], vc1[3]));
                unsigned hw0 = cvt2(hA.x, hA.y);   // hids 4q+{0,1}
                unsigned hw1 = cvt2(hB.x, hB.y);   // hids 4q+{2,3}
                unsigned hw2 = cvt2(hC.x, hC.y);   // hids 16+4q+{0,1}
                unsigned hw3 = cvt2(hD.x, hD.y);   // hids 16+4q+{2,3}
                xpose_pair(hw0, hw2);   // hw0 -> B elems {0,1}, hw2 -> {4,5}
                xpose_pair(hw1, hw3);   // hw1 -> B elems {2,3}, hw3 -> {6,7}
                BA.w[0] = hw0; BA.w[1] = hw1; BA.w[2] = hw2; BA.w[3] = hw3;
                bA = BA.v;
            }
            // ---- activations + pack + permlane transform, tile B ----
            {
                f32x2 hA = gru_act2(mk2(cR0B[0], cR0B[1]), mk2(cZ0B[0], cZ0B[1]),
                                    mk2(cN0B[0], cN0B[1]), mk2(vc0[0], vc0[1]));
                f32x2 hB = gru_act2(mk2(cR0B[2], cR0B[3]), mk2(cZ0B[2], cZ0B[3]),
                                    mk2(cN0B[2], cN0B[3]), mk2(vc0[2], vc0[3]));
                f32x2 hC = gru_act2(mk2(cR1B[0], cR1B[1]), mk2(cZ1B[0], cZ1B[1]),
                                    mk2(cN1B[0], cN1B[1]), mk2(vc1[0], vc1[1]));
                f32x2 hD = gru_act2(mk2(cR1B[2], cR1B[3]), mk2(cZ1B[2], cZ1B[3]),
                                    mk2(cN1B[2], cN1B[3]), mk2(vc1[2], vc1[3]));
                unsigned hw0 = cvt2(hA.x, hA.y);
                unsigned hw1 = cvt2(hB.x, hB.y);
                unsigned hw2 = cvt2(hC.x, hC.y);
                unsigned hw3 = cvt2(hD.x, hD.y);
                xpose_pair(hw0, hw2);
                xpose_pair(hw1, hw3);
                BB.w[0] = hw0; BB.w[1] = hw1; BB.w[2] = hw2; BB.w[3] = hw3;
                bB = BB.v;
            }
        }

        // ---- FC: out^T = fc_w @ h5^T + fc_b, both tiles (regs only) ----
        f32x4 o0A = mfma16h(F0, bA, OB0);
        f32x4 o1A = mfma16h(F1, bA, OB1);
        f32x4 o0B = mfma16h(F0, bB, OB0);
        f32x4 o1B = mfma16h(F1, bB, OB1);

        // lane holds out[batch][emb = t*16 + q*4 + i]
        float* opA = out + (size_t)(rowBase + n0) * 32;
        float* opB = out + (size_t)(rowBase + 16 + n0) * 32;
        *(f32x4*)(opA + 0  + q * 4) = o0A;
        *(f32x4*)(opA + 16 + q * 4) = o1A;
        *(f32x4*)(opB + 0  + q * 4) = o0B;
        *(f32x4*)(opB + 16 + q * 4) = o1B;
    }
}

extern "C" void kernel_launch(void* const* d_in, const int* in_sizes, int n_in,
                              void* d_out, int out_size, void* d_ws, size_t ws_size,
                              hipStream_t stream) {
    (void)n_in; (void)d_ws; (void)ws_size; (void)out_size;
    const float* x    = (const float*)d_in[0];
    const float* w_ih = (const float*)d_in[1];
    // d_in[2] = w_hh: unused (h0 == 0, T == 1)
    const float* b_ih = (const float*)d_in[3];
    const float* b_hh = (const float*)d_in[4];
    const float* fc_w = (const float*)d_in[5];
    const float* fc_b = (const float*)d_in[6];
    float* out = (float*)d_out;

    const int batch  = in_sizes[0] / 32;   // 1048576
    const int nPairs = batch / 32;         // 32768 tile-pairs (2 x 16 rows)

    // 1024 blocks x 512 thr: LDS 33280 B; launch_bounds(512,5) caps combined
    // VGPR+acc at ~96-102 -> target 5 waves/SIMD (vs 4).  FETCH_SIZE is the
    // spill tripwire.  8192 waves, 4 pairs/wave.
    gru_fused<<<1024, NT, 0, stream>>>(x, w_ih, b_ih, b_hh, fc_w, fc_b, out, nPairs);
}

// Round 14
// 100.700 us; speedup vs baseline: 1.1541x; 1.1023x over previous
//
#include <hip/hip_runtime.h>

// ---------------------------------------------------------------------------
// Fused 5-layer GRU (SEQ=1, h0=0) + FC for MI355X (gfx950).  Round 15.
//
// R15: (1) revert R14's (512,5) -> (512,4).  The spill ledger across rounds
// shows VGPR_Count EXCLUDES MFMA accumulators: T=2 combined ~100 regs fits
// the 128 cap ((512,4)); the 96-102 cap of (512,5) spilled ~4-5 regs (FETCH
// 66->80MB, bench 104->111).  Headroom under (512,4) is ~28 regs.
// (2) spend 16 of those regs on next-pair x PREFETCH: after cvt consumes the
// current pair's 4 f32x4 x-registers, issue the 4 global_load_dwordx4 for
// pair t+stride into them; the ~500-900cy HBM latency hides under the
// ~2000cy 5-layer loop instead of serializing at loop top (T14 regime:
// long compute phase, moderate occupancy).  Clamped address on the last
// iteration.  This is the one latency term never yet addressed.
// If FETCH stays ~66MB but dur doesn't move, the kernel is at its
// VALU-issue structural floor (activation math is exact-GRU minimal).
//
// Kept from R12: XOR-swizzled stride-32 LDS weights (33280 B), grid 1024.
// Kept from R11: FC weights + fc_b in registers.
// Kept from R10: single-plane fp16 MFMA, cvt_pkrtz pack, permlane C->B.
// Kept from R9: hardware v_rcp, exp2 scales folded into staged weights.
// Kept from R7: 2-tile interleave, shared A-frag/bias reads, MFMA D!=C init.
//
// Orientation: C^T = W @ h^T  (A = weight tile [gate][k], B = h^T [k][batch]).
// MFMA C/D layout (16x16x32): col = lane&15 = BATCH, row = q*4+i = gate row.
// ---------------------------------------------------------------------------

typedef __attribute__((ext_vector_type(8))) _Float16 f16x8;
typedef __attribute__((ext_vector_type(4))) float f32x4;
typedef __attribute__((ext_vector_type(2))) float f32x2;
typedef __attribute__((ext_vector_type(4))) unsigned int u32x4;

#define NLAYER 5
#define NT     512 // block threads (8 waves)

__device__ __forceinline__ float fexp2(float x) {
#if __has_builtin(__builtin_amdgcn_exp2f)
    return __builtin_amdgcn_exp2f(x);
#else
    return exp2f(x);
#endif
}
__device__ __forceinline__ float frcp(float x) {
#if __has_builtin(__builtin_amdgcn_rcpf)
    return __builtin_amdgcn_rcpf(x);
#else
    return 1.0f / x;
#endif
}

// pack two f32 -> two fp16 (RTZ) in one word; rel err <= 2^-10.
__device__ __forceinline__ unsigned cvt2(float f0, float f1) {
    unsigned r;
    asm("v_cvt_pkrtz_f16_f32 %0, %1, %2" : "=v"(r) : "v"(f0), "v"(f1));
    return r;
}

__device__ __forceinline__ f32x4 mfma16h(f16x8 a, f16x8 b, f32x4 c) {
    return __builtin_amdgcn_mfma_f32_16x16x32_f16(a, b, c, 0, 0, 0);
}

// In-register 16-lane-group exchange (gfx950):
//   in : x = [X0,X1,X2,X3], y = [Y0,Y1,Y2,Y3]   (16-lane groups)
//   out: x = [X0,X2,Y0,Y2], y = [X1,X3,Y1,Y3]
__device__ __forceinline__ void xpose_pair(unsigned &x, unsigned &y) {
    asm("v_permlane32_swap_b32 %0, %1" : "+v"(x), "+v"(y));
    asm("v_permlane16_swap_b32 %0, %1" : "+v"(x), "+v"(y));
}

__device__ __forceinline__ f32x2 mk2(float a, float b) { f32x2 v; v.x = a; v.y = b; return v; }
__device__ __forceinline__ f32x2 exp2v(f32x2 v) { f32x2 r; r.x = fexp2(v.x); r.y = fexp2(v.y); return r; }
__device__ __forceinline__ f32x2 rcpv(f32x2 v)  { f32x2 r; r.x = frcp(v.x);  r.y = frcp(v.y);  return r; }

// h = (1-z)*n = sigmoid(-az)*tanh(an + sigmoid(ar)*cn)
//   = [ez*(1-en)] / [(1+ez)*(1+en)]
// Args are PRE-SCALED at staging: ar,az by -log2e; an,cn by -2log2e.
__device__ __forceinline__ f32x2 gru_act2(f32x2 ar, f32x2 az, f32x2 an, f32x2 cn) {
    f32x2 er  = exp2v(ar);
    f32x2 ez  = exp2v(az);
    f32x2 r   = rcpv(er + 1.0f);
    f32x2 a2  = an + r * cn;
    f32x2 en  = exp2v(a2);
    f32x2 num = ez - ez * en;
    f32x2 den = (ez + 1.0f) * (en + 1.0f);
    return num * rcpv(den);
}

struct __align__(16) Lds {
    _Float16 wA[NLAYER * 96 * 32];                // 30720 B  [l][gate-row][k], XOR-swizzled
    float bsum[NLAYER * 96];                      //  1920 B  scaled biases
    float cn_[NLAYER * 32];                       //   640 B  scaled b_hh n-gate
};                                                // total 33280 B

union BU { u32x4 w; f16x8 v; };

__global__ __launch_bounds__(NT, 4) void gru_fused(
    const float* __restrict__ x, const float* __restrict__ w_ih,
    const float* __restrict__ b_ih, const float* __restrict__ b_hh,
    const float* __restrict__ fc_w, const float* __restrict__ fc_b,
    float* __restrict__ out, int nPairs)
{
    __shared__ Lds s;
    const int tid = threadIdx.x;
    const float NL2E = -1.4426950408889634f;  // -log2(e)

    // ---- stage GRU weights / biases into LDS (once per block), pre-scaled.
    // Swizzle: element i stored at i ^ ((row&7)<<3). ----
    for (int i = tid; i < NLAYER * 96 * 32; i += NT) {
        int r = i >> 5;
        int g = r % 96;                         // gate row within layer
        float sc = (g < 64) ? NL2E : 2.0f * NL2E;
        s.wA[i ^ ((r & 7) << 3)] = (_Float16)(w_ih[i] * sc);   // RNE, rel 2^-11
    }
    for (int i = tid; i < NLAYER * 96; i += NT) {
        int c = i % 96;
        float v = b_ih[i] + (c < 64 ? b_hh[i] : 0.0f);
        s.bsum[i] = v * ((c < 64) ? NL2E : 2.0f * NL2E);
    }
    for (int i = tid; i < NLAYER * 32; i += NT) {
        int l = i >> 5, c = i & 31;
        s.cn_[i] = b_hh[l * 96 + 64 + c] * (2.0f * NL2E);
    }
    __syncthreads();

    const int lane = tid & 63;
    const int n0 = lane & 15;     // batch-col (B n-index / C col); A row m
    const int q  = lane >> 4;     // k-group (A/B), row-group (C/D)
    const int aBase = ((n0 * 32) + q * 8) ^ ((n0 & 7) << 3);  // swizzled A-frag idx

    // ---- FC weights + bias in registers (loop-invariant, 16 VGPR) ----
    f16x8 F0, F1;
    {
        const float* p0 = fc_w + (size_t)(n0 * 32 + q * 8);
        const float* p1 = fc_w + (size_t)((16 + n0) * 32 + q * 8);
        f32x4 a0 = *(const f32x4*)p0, a1 = *(const f32x4*)(p0 + 4);
        f32x4 b0 = *(const f32x4*)p1, b1 = *(const f32x4*)(p1 + 4);
        BU U0, U1;
        U0.w[0] = cvt2(a0[0], a0[1]); U0.w[1] = cvt2(a0[2], a0[3]);
        U0.w[2] = cvt2(a1[0], a1[1]); U0.w[3] = cvt2(a1[2], a1[3]);
        U1.w[0] = cvt2(b0[0], b0[1]); U1.w[1] = cvt2(b0[2], b0[3]);
        U1.w[2] = cvt2(b1[0], b1[1]); U1.w[3] = cvt2(b1[2], b1[3]);
        F0 = U0.v; F1 = U1.v;
    }
    f32x4 OB0 = *(const f32x4*)(fc_b + q * 4);
    f32x4 OB1 = *(const f32x4*)(fc_b + 16 + q * 4);

    const int waveId  = (int)((blockIdx.x * (unsigned)NT + tid) >> 6);
    const int nWavesG = (int)((gridDim.x * (unsigned)NT) >> 6);

    // ---- preload first pair's x (4 x dwordx4 = 16 VGPR) ----
    f32x4 xaA, xbA, xaB, xbB;
    if (waveId < nPairs) {
        const float* xpA = x + (size_t)(waveId * 32 + n0) * 32 + q * 8;
        const float* xpB = x + (size_t)(waveId * 32 + 16 + n0) * 32 + q * 8;
        xaA = *(const f32x4*)xpA; xbA = *(const f32x4*)(xpA + 4);
        xaB = *(const f32x4*)xpB; xbB = *(const f32x4*)(xpB + 4);
    }

    for (int t = waveId; t < nPairs; t += nWavesG) {
        const int rowBase = t * 32;  // tile A rows +0..15, tile B rows +16..31

        // ---- convert prefetched x to fp16 B-frags (frees xa*/xb*) ----
        BU BA, BB;
        BA.w[0] = cvt2(xaA[0], xaA[1]); BA.w[1] = cvt2(xaA[2], xaA[3]);
        BA.w[2] = cvt2(xbA[0], xbA[1]); BA.w[3] = cvt2(xbA[2], xbA[3]);
        BB.w[0] = cvt2(xaB[0], xaB[1]); BB.w[1] = cvt2(xaB[2], xaB[3]);
        BB.w[2] = cvt2(xbB[0], xbB[1]); BB.w[3] = cvt2(xbB[2], xbB[3]);
        f16x8 bA = BA.v, bB = BB.v;

        // ---- issue next pair's x loads now; they complete under the
        // 5-layer compute below (clamped to current t on the last iter) ----
        {
            int tn = t + nWavesG;
            int tl = (tn < nPairs) ? tn : t;
            const float* xpA = x + (size_t)(tl * 32 + n0) * 32 + q * 8;
            const float* xpB = x + (size_t)(tl * 32 + 16 + n0) * 32 + q * 8;
            xaA = *(const f32x4*)xpA; xbA = *(const f32x4*)(xpA + 4);
            xaB = *(const f32x4*)xpB; xbB = *(const f32x4*)(xpB + 4);
        }

        #pragma unroll
        for (int l = 0; l < NLAYER; ++l) {
            const _Float16* wb = s.wA + l * 96 * 32;
            const float* bs = s.bsum + l * 96;

            f32x4 cR0A, cR1A, cZ0A, cZ1A, cN0A, cN1A;
            f32x4 cR0B, cR1B, cZ0B, cZ1B, cN0B, cN1B;

            // per gate-tile: 1 swizzled A-frag LDS read + 1 bias read -> 2
            // MFMAs (one per batch-tile), each initing from bias via D != C.
            {
                f16x8 a = *(const f16x8*)(wb + aBase + 0 * 512);
                f32x4 cb = *(const f32x4*)(bs + 0 + q * 4);
                cR0A = mfma16h(a, bA, cb);
                cR0B = mfma16h(a, bB, cb);
            }
            {
                f16x8 a = *(const f16x8*)(wb + aBase + 1 * 512);
                f32x4 cb = *(const f32x4*)(bs + 16 + q * 4);
                cR1A = mfma16h(a, bA, cb);
                cR1B = mfma16h(a, bB, cb);
            }
            {
                f16x8 a = *(const f16x8*)(wb + aBase + 2 * 512);
                f32x4 cb = *(const f32x4*)(bs + 32 + q * 4);
                cZ0A = mfma16h(a, bA, cb);
                cZ0B = mfma16h(a, bB, cb);
            }
            {
                f16x8 a = *(const f16x8*)(wb + aBase + 3 * 512);
                f32x4 cb = *(const f32x4*)(bs + 48 + q * 4);
                cZ1A = mfma16h(a, bA, cb);
                cZ1B = mfma16h(a, bB, cb);
            }
            {
                f16x8 a = *(const f16x8*)(wb + aBase + 4 * 512);
                f32x4 cb = *(const f32x4*)(bs + 64 + q * 4);
                cN0A = mfma16h(a, bA, cb);
                cN0B = mfma16h(a, bB, cb);
            }
            {
                f16x8 a = *(const f16x8*)(wb + aBase + 5 * 512);
                f32x4 cb = *(const f32x4*)(bs + 80 + q * 4);
                cN1A = mfma16h(a, bA, cb);
                cN1B = mfma16h(a, bB, cb);
            }

            f32x4 vc0 = *(const f32x4*)(s.cn_ + l * 32 + 0  + q * 4);
            f32x4 vc1 = *(const f32x4*)(s.cn_ + l * 32 + 16 + q * 4);

            // ---- activations + pack + permlane transform, tile A ----
            {
                f32x2 hA = gru_act2(mk2(cR0A[0], cR0A[1]), mk2(cZ0A[0], cZ0A[1]),
                                    mk2(cN0A[0], cN0A[1]), mk2(vc0[0], vc0[1]));
                f32x2 hB = gru_act2(mk2(cR0A[2], cR0A[3]), mk2(cZ0A[2], cZ0A[3]),
                                    mk2(cN0A[2], cN0A[3]), mk2(vc0[2], vc0[3]));
                f32x2 hC = gru_act2(mk2(cR1A[0], cR1A[1]), mk2(cZ1A[0], cZ1A[1]),
                                    mk2(cN1A[0], cN1A[1]), mk2(vc1[0], vc1[1]));
                f32x2 hD = gru_act2(mk2(cR1A[2], cR1A[3]), mk2(cZ1A[2], cZ1A[3]),
                                    mk2(cN1A[2], cN1A[3]), mk2(vc1[2], vc1[3]));
                unsigned hw0 = cvt2(hA.x, hA.y);   // hids 4q+{0,1}
                unsigned hw1 = cvt2(hB.x, hB.y);   // hids 4q+{2,3}
                unsigned hw2 = cvt2(hC.x, hC.y);   // hids 16+4q+{0,1}
                unsigned hw3 = cvt2(hD.x, hD.y);   // hids 16+4q+{2,3}
                xpose_pair(hw0, hw2);   // hw0 -> B elems {0,1}, hw2 -> {4,5}
                xpose_pair(hw1, hw3);   // hw1 -> B elems {2,3}, hw3 -> {6,7}
                BA.w[0] = hw0; BA.w[1] = hw1; BA.w[2] = hw2; BA.w[3] = hw3;
                bA = BA.v;
            }
            // ---- activations + pack + permlane transform, tile B ----
            {
                f32x2 hA = gru_act2(mk2(cR0B[0], cR0B[1]), mk2(cZ0B[0], cZ0B[1]),
                                    mk2(cN0B[0], cN0B[1]), mk2(vc0[0], vc0[1]));
                f32x2 hB = gru_act2(mk2(cR0B[2], cR0B[3]), mk2(cZ0B[2], cZ0B[3]),
                                    mk2(cN0B[2], cN0B[3]), mk2(vc0[2], vc0[3]));
                f32x2 hC = gru_act2(mk2(cR1B[0], cR1B[1]), mk2(cZ1B[0], cZ1B[1]),
                                    mk2(cN1B[0], cN1B[1]), mk2(vc1[0], vc1[1]));
                f32x2 hD = gru_act2(mk2(cR1B[2], cR1B[3]), mk2(cZ1B[2], cZ1B[3]),
                                    mk2(cN1B[2], cN1B[3]), mk2(vc1[2], vc1[3]));
                unsigned hw0 = cvt2(hA.x, hA.y);
                unsigned hw1 = cvt2(hB.x, hB.y);
                unsigned hw2 = cvt2(hC.x, hC.y);
                unsigned hw3 = cvt2(hD.x, hD.y);
                xpose_pair(hw0, hw2);
                xpose_pair(hw1, hw3);
                BB.w[0] = hw0; BB.w[1] = hw1; BB.w[2] = hw2; BB.w[3] = hw3;
                bB = BB.v;
            }
        }

        // ---- FC: out^T = fc_w @ h5^T + fc_b, both tiles (regs only) ----
        f32x4 o0A = mfma16h(F0, bA, OB0);
        f32x4 o1A = mfma16h(F1, bA, OB1);
        f32x4 o0B = mfma16h(F0, bB, OB0);
        f32x4 o1B = mfma16h(F1, bB, OB1);

        // lane holds out[batch][emb = t*16 + q*4 + i]
        float* opA = out + (size_t)(rowBase + n0) * 32;
        float* opB = out + (size_t)(rowBase + 16 + n0) * 32;
        *(f32x4*)(opA + 0  + q * 4) = o0A;
        *(f32x4*)(opA + 16 + q * 4) = o1A;
        *(f32x4*)(opB + 0  + q * 4) = o0B;
        *(f32x4*)(opB + 16 + q * 4) = o1B;
    }
}

extern "C" void kernel_launch(void* const* d_in, const int* in_sizes, int n_in,
                              void* d_out, int out_size, void* d_ws, size_t ws_size,
                              hipStream_t stream) {
    (void)n_in; (void)d_ws; (void)ws_size; (void)out_size;
    const float* x    = (const float*)d_in[0];
    const float* w_ih = (const float*)d_in[1];
    // d_in[2] = w_hh: unused (h0 == 0, T == 1)
    const float* b_ih = (const float*)d_in[3];
    const float* b_hh = (const float*)d_in[4];
    const float* fc_w = (const float*)d_in[5];
    const float* fc_b = (const float*)d_in[6];
    float* out = (float*)d_out;

    const int batch  = in_sizes[0] / 32;   // 1048576
    const int nPairs = batch / 32;         // 32768 tile-pairs (2 x 16 rows)

    // 1024 blocks x 512 thr: LDS 33280 B; launch_bounds(512,4) = the proven
    // no-spill cap (combined demand ~116 incl. 16 prefetch regs < 128).
    // FETCH_SIZE is the spill tripwire.  8192 waves, 4 pairs/wave.
    gru_fused<<<1024, NT, 0, stream>>>(x, w_ih, b_ih, b_hh, fc_w, fc_b, out, nPairs);
}